// Round 1
// baseline (380.221 us; speedup 1.0000x reference)
//
#include <hip/hip_runtime.h>

// Problem: N=8192 points, D=256 dims, fp32 inputs (L2-normalized rows).
// out[0] = sum_{i,j} [ (s<1-1e-5 ? 1-s : 0) + (s>0.5 ? s : 0) ] / N,  s = q_i . k_j
// out[1] = -mean_i log( sqrt( sum_d (q_i[d] - q_nn(i)[d] + 1e-6)^2 ) ),
//          nn(i) = argmax_{j != i} q_i . q_j   (first index on ties)

typedef __attribute__((ext_vector_type(8))) short bf16x8;
typedef __attribute__((ext_vector_type(4))) float f32x4;

static constexpr int NPTS = 8192;
static constexpr int DIM  = 256;

__device__ __forceinline__ unsigned short f2bf(float f) {
    unsigned u = __float_as_uint(f);
    u += 0x7FFFu + ((u >> 16) & 1u);   // RNE; inputs are finite, no NaN handling needed
    return (unsigned short)(u >> 16);
}

// ---- fp32 -> bf16 conversion of q and k -------------------------------------
__global__ __launch_bounds__(256) void convert_kernel(
    const float* __restrict__ q, const float* __restrict__ k,
    unsigned short* __restrict__ qbf, unsigned short* __restrict__ kbf)
{
    const int idx = blockIdx.x * 256 + threadIdx.x;      // 0 .. 2*N*D/4-1
    const int half = NPTS * DIM / 4;                     // 524288 float4's per tensor
    const float* src = (idx < half) ? q : k;
    unsigned short* dst = (idx < half) ? qbf : kbf;
    const int i = (idx < half) ? idx : idx - half;
    float4 v = reinterpret_cast<const float4*>(src)[i];
    ushort4 o;
    o.x = f2bf(v.x); o.y = f2bf(v.y); o.z = f2bf(v.z); o.w = f2bf(v.w);
    reinterpret_cast<ushort4*>(dst)[i] = o;
}

// ---- fused GEMM (128x128 tile, BK=64, 4 waves, mfma 16x16x32 bf16) ----------
// MODE 0: loss epilogue -> loss_partial[blockIdx]
// MODE 1: per-row argmax over this block's 128 cols -> part[row*64 + bx] (packed u64)
template<int MODE>
__global__ __launch_bounds__(256) void sim_kernel(
    const unsigned short* __restrict__ A,   // [N][D] bf16 bits
    const unsigned short* __restrict__ B,   // [N][D] bf16 bits
    float* __restrict__ loss_partial,
    unsigned long long* __restrict__ part)
{
    __shared__ __align__(16) unsigned short ldsA[128][72];   // +8 bf16 pad (16B) per row
    __shared__ __align__(16) unsigned short ldsB[128][72];
    __shared__ unsigned long long lds_pack[4][64];
    __shared__ float red[4];

    const int t  = threadIdx.x;
    const int l  = t & 63;
    const int w  = t >> 6;
    const int bid = blockIdx.x;
    const int bx = bid & 63;
    const int by = bid >> 6;
    const int rowbase = by << 7;
    const int colbase = bx << 7;
    const int wr = (w >> 1) << 6;   // wave row offset: 0 or 64
    const int wc = (w & 1) << 6;    // wave col offset: 0 or 64

    f32x4 acc[4][4];
#pragma unroll
    for (int m = 0; m < 4; m++)
#pragma unroll
        for (int n = 0; n < 4; n++) acc[m][n] = (f32x4){0.f, 0.f, 0.f, 0.f};

    const int cr = t >> 3;   // staging chunk row (0..31, +i*32)
    const int cs = t & 7;    // staging 16B slot within row

    for (int kb = 0; kb < DIM; kb += 64) {
        ulonglong2 ra[4], rb[4];
#pragma unroll
        for (int i = 0; i < 4; i++) {
            const int r = cr + i * 32;
            ra[i] = *reinterpret_cast<const ulonglong2*>(&A[(rowbase + r) * DIM + kb + cs * 8]);
            rb[i] = *reinterpret_cast<const ulonglong2*>(&B[(colbase + r) * DIM + kb + cs * 8]);
        }
        __syncthreads();   // previous iteration's LDS reads done
#pragma unroll
        for (int i = 0; i < 4; i++) {
            const int r = cr + i * 32;
            *reinterpret_cast<ulonglong2*>(&ldsA[r][cs * 8]) = ra[i];
            *reinterpret_cast<ulonglong2*>(&ldsB[r][cs * 8]) = rb[i];
        }
        __syncthreads();
#pragma unroll
        for (int kk = 0; kk < 2; kk++) {
            bf16x8 af[4], bfr[4];
#pragma unroll
            for (int m = 0; m < 4; m++)
                af[m] = *reinterpret_cast<const bf16x8*>(&ldsA[wr + m * 16 + (l & 15)][kk * 32 + (l >> 4) * 8]);
#pragma unroll
            for (int n = 0; n < 4; n++)
                bfr[n] = *reinterpret_cast<const bf16x8*>(&ldsB[wc + n * 16 + (l & 15)][kk * 32 + (l >> 4) * 8]);
#pragma unroll
            for (int m = 0; m < 4; m++)
#pragma unroll
                for (int n = 0; n < 4; n++)
                    acc[m][n] = __builtin_amdgcn_mfma_f32_16x16x32_bf16(af[m], bfr[n], acc[m][n], 0, 0, 0);
        }
    }

    if (MODE == 0) {
        // loss: f(s) summed over the whole tile, hierarchical reduction
        const float POS_THR = (float)(1.0 - 1e-5);
        float s = 0.f;
#pragma unroll
        for (int m = 0; m < 4; m++)
#pragma unroll
            for (int n = 0; n < 4; n++)
#pragma unroll
                for (int v = 0; v < 4; v++) {
                    const float x = acc[m][n][v];
                    s += (x < POS_THR ? 1.0f - x : 0.0f) + (x > 0.5f ? x : 0.0f);
                }
#pragma unroll
        for (int off = 32; off; off >>= 1) s += __shfl_down(s, off);
        if (l == 0) red[w] = s;
        __syncthreads();
        if (t == 0) loss_partial[bid] = red[0] + red[1] + red[2] + red[3];
    } else {
        // argmax: D row = (l>>4)*4 + v (+m*16), D col = l&15 (+n*16)
#pragma unroll
        for (int m = 0; m < 4; m++)
#pragma unroll
            for (int v = 0; v < 4; v++) {
                const int rlocal = m * 16 + ((l >> 4) << 2) + v;    // 0..63 within wave
                const int grow = rowbase + wr + rlocal;
                float best = -3.0f;
                int bcol = 0x7FFFFFFF;
#pragma unroll
                for (int n = 0; n < 4; n++) {
                    const int gcol = colbase + wc + n * 16 + (l & 15);
                    const float x = acc[m][n][v];
                    const bool valid = (gcol != grow);              // diagonal excluded
                    if (valid && (x > best || (x == best && gcol < bcol))) { best = x; bcol = gcol; }
                }
#pragma unroll
                for (int mask = 1; mask < 16; mask <<= 1) {         // reduce the 16 lanes holding this row
                    const float ob = __shfl_xor(best, mask);
                    const int   oc = __shfl_xor(bcol, mask);
                    if (ob > best || (ob == best && oc < bcol)) { best = ob; bcol = oc; }
                }
                if ((l & 15) == 0) {
                    unsigned ub = __float_as_uint(best);
                    unsigned key = (ub & 0x80000000u) ? ~ub : (ub | 0x80000000u);  // order-preserving
                    lds_pack[w][rlocal] = ((unsigned long long)key << 32) | (unsigned)(~bcol);
                }
            }
        __syncthreads();
        if (t < 128) {
            const int half = t >> 6;                      // waves {0,1} rows 0-63, {2,3} rows 64-127
            const unsigned long long p0 = lds_pack[half * 2][t & 63];
            const unsigned long long p1 = lds_pack[half * 2 + 1][t & 63];
            const unsigned long long p = (p0 > p1) ? p0 : p1;
            part[(unsigned)(rowbase + t) * 64u + (unsigned)bx] = p;
        }
    }
}

// ---- per-row: combine 64 tile-maxes -> nn idx -> exact fp32 distance -> -log ----
__global__ __launch_bounds__(256) void nn_reg_kernel(
    const float* __restrict__ q, const unsigned long long* __restrict__ part,
    float* __restrict__ reg_partial)
{
    __shared__ float red[4];
    const int t = threadIdx.x, l = t & 63, w = t >> 6;
    const int row = blockIdx.x * 4 + w;
    unsigned long long p = part[(unsigned)row * 64u + (unsigned)l];
#pragma unroll
    for (int mask = 1; mask < 64; mask <<= 1) {
        const unsigned long long o = __shfl_xor(p, mask);
        if (o > p) p = o;
    }
    const int col = (int)(~(unsigned)(p & 0xFFFFFFFFull));
    const float4* q4 = reinterpret_cast<const float4*>(q);
    const float4 a = q4[row * 64 + l];
    const float4 b = q4[col * 64 + l];
    const float dx = a.x - b.x + 1e-6f;
    const float dy = a.y - b.y + 1e-6f;
    const float dz = a.z - b.z + 1e-6f;
    const float dw = a.w - b.w + 1e-6f;
    float s = dx * dx + dy * dy + dz * dz + dw * dw;
#pragma unroll
    for (int mask = 32; mask; mask >>= 1) s += __shfl_xor(s, mask);
    if (l == 0) red[w] = -0.5f * logf(s);   // -log(sqrt(s))
    __syncthreads();
    if (t == 0) reg_partial[blockIdx.x] = red[0] + red[1] + red[2] + red[3];
}

// ---- final double-precision reduction of partials ---------------------------
__global__ __launch_bounds__(256) void finalize_kernel(
    const float* __restrict__ lp, const float* __restrict__ rp, float* __restrict__ out)
{
    const int t = threadIdx.x, l = t & 63, w = t >> 6;
    double s1 = 0.0, s2 = 0.0;
    for (int i = t; i < 4096; i += 256) s1 += (double)lp[i];
    for (int i = t; i < 2048; i += 256) s2 += (double)rp[i];
#pragma unroll
    for (int mask = 32; mask; mask >>= 1) {
        s1 += __shfl_xor(s1, mask);
        s2 += __shfl_xor(s2, mask);
    }
    __shared__ double r1[4], r2[4];
    if (l == 0) { r1[w] = s1; r2[w] = s2; }
    __syncthreads();
    if (t == 0) {
        out[0] = (float)((r1[0] + r1[1] + r1[2] + r1[3]) / (double)NPTS);
        out[1] = (float)((r2[0] + r2[1] + r2[2] + r2[3]) / (double)NPTS);
    }
}

extern "C" void kernel_launch(void* const* d_in, const int* in_sizes, int n_in,
                              void* d_out, int out_size, void* d_ws, size_t ws_size,
                              hipStream_t stream)
{
    const float* q = (const float*)d_in[0];
    const float* k = (const float*)d_in[1];
    char* ws = (char*)d_ws;
    unsigned short* qbf = (unsigned short*)ws;                          // 4 MB
    unsigned short* kbf = (unsigned short*)(ws + (4u << 20));           // 4 MB
    unsigned long long* part = (unsigned long long*)(ws + (8u << 20));  // 8192*64*8 = 4 MB
    float* lp = (float*)(ws + (12u << 20));                             // 4096 floats
    float* rp = (float*)(ws + (12u << 20) + (16u << 10));               // 2048 floats
    float* out = (float*)d_out;

    convert_kernel<<<4096, 256, 0, stream>>>(q, k, qbf, kbf);
    sim_kernel<0><<<4096, 256, 0, stream>>>(qbf, kbf, lp, nullptr);     // loss over q.k^T
    sim_kernel<1><<<4096, 256, 0, stream>>>(qbf, qbf, nullptr, part);   // argmax over q.q^T
    nn_reg_kernel<<<2048, 256, 0, stream>>>(q, part, rp);
    finalize_kernel<<<1, 256, 0, stream>>>(lp, rp, out);
}

// Round 2
// 145.723 us; speedup vs baseline: 2.6092x; 2.6092x over previous
//
#include <hip/hip_runtime.h>

// Problem: N=8192 points, D=256 dims, fp32 inputs (L2-normalized rows).
// out[0] = sum_{i,j} [ (s<1-1e-5 ? 1-s : 0) + (s>0.5 ? s : 0) ] / N,  s = q_i . k_j
// out[1] = -mean_i log( sqrt( sum_d (q_i[d] - q_nn(i)[d] + 1e-6)^2 ) ),
//          nn(i) = argmax_{j != i} q_i . q_j   (first index on ties)

typedef __attribute__((ext_vector_type(8))) short bf16x8;
typedef __attribute__((ext_vector_type(4))) float f32x4;

static constexpr int NPTS = 8192;
static constexpr int DIM  = 256;

__device__ __forceinline__ unsigned short f2bf(float f) {
    unsigned u = __float_as_uint(f);
    u += 0x7FFFu + ((u >> 16) & 1u);   // RNE; inputs are finite
    return (unsigned short)(u >> 16);
}

// async global->LDS, 16B per lane; LDS dest = wave-uniform base + lane*16
__device__ __forceinline__ void gload16(const unsigned short* g, unsigned short* lds) {
    __builtin_amdgcn_global_load_lds(
        (const __attribute__((address_space(1))) unsigned int*)g,
        (__attribute__((address_space(3))) unsigned int*)lds, 16, 0, 0);
}

// ---- fp32 -> bf16 conversion of q and k -------------------------------------
__global__ __launch_bounds__(256) void convert_kernel(
    const float* __restrict__ q, const float* __restrict__ k,
    unsigned short* __restrict__ qbf, unsigned short* __restrict__ kbf)
{
    const int idx = blockIdx.x * 256 + threadIdx.x;
    const int half = NPTS * DIM / 4;
    const float* src = (idx < half) ? q : k;
    unsigned short* dst = (idx < half) ? qbf : kbf;
    const int i = (idx < half) ? idx : idx - half;
    float4 v = reinterpret_cast<const float4*>(src)[i];
    ushort4 o;
    o.x = f2bf(v.x); o.y = f2bf(v.y); o.z = f2bf(v.z); o.w = f2bf(v.w);
    reinterpret_cast<ushort4*>(dst)[i] = o;
}

// ---- fused GEMM (128x128 tile, BK=64, 4 waves, mfma 16x16x32 bf16) ----------
// Staging: global_load_lds (no reg staging -> no spill). LDS stored swizzled:
// physical elem = logical elem ^ (8*(row&7)) within each 64-elem row; the
// inverse swizzle is applied to the per-lane GLOBAL source address (rule #21),
// and the same XOR is applied on ds_read -> ~2-way bank aliasing (free).
// MODE 0: loss epilogue -> loss_partial[blockIdx]
// MODE 1: per-row argmax over this block's 128 cols -> part[bx*N + row] (packed u64)
template<int MODE>
__global__ __launch_bounds__(256) void sim_kernel(
    const unsigned short* __restrict__ A,   // [N][D] bf16 bits
    const unsigned short* __restrict__ B,   // [N][D] bf16 bits
    float* __restrict__ loss_partial,
    unsigned long long* __restrict__ part)
{
    __shared__ __align__(16) unsigned short ldsA[128 * 64];
    __shared__ __align__(16) unsigned short ldsB[128 * 64];
    __shared__ unsigned long long lds_pack[4][64];
    __shared__ float red[4];

    const int t  = threadIdx.x;
    const int l  = t & 63;
    const int w  = t >> 6;
    const int bid = blockIdx.x;
    const int bx = bid & 63;
    const int by = bid >> 6;
    const int rowbase = by << 7;
    const int colbase = bx << 7;
    const int wr = (w >> 1) << 6;   // wave row offset: 0 or 64
    const int wc = (w & 1) << 6;    // wave col offset: 0 or 64

    // staging: wave w covers rows [w*32, w*32+32); issue j covers 8 rows.
    // lane i writes physical LDS bytes base + i*16 -> row = +i/8, slot = i%8.
    // logical col element = 8*((i&7) ^ (i>>3))  (inverse of the read swizzle)
    const int srow = w * 32 + (l >> 3);
    const int scol = 8 * ((l & 7) ^ (l >> 3));
    const unsigned short* gA = A + (size_t)(rowbase + srow) * DIM + scol;
    const unsigned short* gB = B + (size_t)(colbase + srow) * DIM + scol;

    f32x4 acc[4][4];
#pragma unroll
    for (int m = 0; m < 4; m++)
#pragma unroll
        for (int n = 0; n < 4; n++) acc[m][n] = (f32x4){0.f, 0.f, 0.f, 0.f};

    const int fr = l & 15;     // fragment row within 16
    const int c0 = l >> 4;     // k-slot 0..3
    const int sx = l & 7;      // read-side swizzle xor (== row&7 for frag rows)

    for (int kb = 0; kb < DIM / 64; kb++) {
#pragma unroll
        for (int j = 0; j < 4; j++) {
            gload16(gA + (size_t)(j * 8) * DIM, &ldsA[(w * 32 + j * 8) * 64]);
            gload16(gB + (size_t)(j * 8) * DIM, &ldsB[(w * 32 + j * 8) * 64]);
        }
        gA += 64; gB += 64;
        __syncthreads();   // drains vmcnt -> tiles resident
#pragma unroll
        for (int kk = 0; kk < 2; kk++) {
            bf16x8 af[4], bfr[4];
#pragma unroll
            for (int m = 0; m < 4; m++) {
                const int row = wr + m * 16 + fr;
                af[m] = *reinterpret_cast<const bf16x8*>(&ldsA[row * 64 + 8 * ((kk * 4 + c0) ^ sx)]);
            }
#pragma unroll
            for (int n = 0; n < 4; n++) {
                const int row = wc + n * 16 + fr;
                bfr[n] = *reinterpret_cast<const bf16x8*>(&ldsB[row * 64 + 8 * ((kk * 4 + c0) ^ sx)]);
            }
#pragma unroll
            for (int m = 0; m < 4; m++)
#pragma unroll
                for (int n = 0; n < 4; n++)
                    acc[m][n] = __builtin_amdgcn_mfma_f32_16x16x32_bf16(af[m], bfr[n], acc[m][n], 0, 0, 0);
        }
        __syncthreads();   // LDS reads done before next iter's async writes
    }

    if (MODE == 0) {
        const float POS_THR = (float)(1.0 - 1e-5);
        float s = 0.f;
#pragma unroll
        for (int m = 0; m < 4; m++)
#pragma unroll
            for (int n = 0; n < 4; n++)
#pragma unroll
                for (int v = 0; v < 4; v++) {
                    const float x = acc[m][n][v];
                    s += (x < POS_THR ? 1.0f - x : 0.0f) + (x > 0.5f ? x : 0.0f);
                }
#pragma unroll
        for (int off = 32; off; off >>= 1) s += __shfl_down(s, off);
        if (l == 0) red[w] = s;
        __syncthreads();
        if (t == 0) loss_partial[bid] = red[0] + red[1] + red[2] + red[3];
    } else {
        // C/D mapping: col = lane&15 (+n*16), row = (lane>>4)*4 + v (+m*16)
#pragma unroll
        for (int m = 0; m < 4; m++)
#pragma unroll
            for (int v = 0; v < 4; v++) {
                const int rlocal = m * 16 + ((l >> 4) << 2) + v;    // 0..63 within wave
                const int grow = rowbase + wr + rlocal;
                float best = -3.0f;
                int bcol = 0x7FFFFFFF;
#pragma unroll
                for (int n = 0; n < 4; n++) {
                    const int gcol = colbase + wc + n * 16 + (l & 15);
                    const float x = acc[m][n][v];
                    const bool valid = (gcol != grow);              // exclude diagonal
                    if (valid && (x > best || (x == best && gcol < bcol))) { best = x; bcol = gcol; }
                }
#pragma unroll
                for (int mask = 1; mask < 16; mask <<= 1) {         // 16 lanes hold this row
                    const float ob = __shfl_xor(best, mask);
                    const int   oc = __shfl_xor(bcol, mask);
                    if (ob > best || (ob == best && oc < bcol)) { best = ob; bcol = oc; }
                }
                if ((l & 15) == 0) {
                    unsigned ub = __float_as_uint(best);
                    unsigned key = (ub & 0x80000000u) ? ~ub : (ub | 0x80000000u);  // order-preserving
                    lds_pack[w][rlocal] = ((unsigned long long)key << 32) | (unsigned)(~bcol);
                }
            }
        __syncthreads();
        if (t < 128) {
            const int half = t >> 6;                      // waves {0,1}: rows 0-63; {2,3}: 64-127
            const unsigned long long p0 = lds_pack[half * 2][t & 63];
            const unsigned long long p1 = lds_pack[half * 2 + 1][t & 63];
            const unsigned long long p = (p0 > p1) ? p0 : p1;
            part[(size_t)bx * NPTS + (unsigned)(rowbase + t)] = p;   // coalesced 1KB/block
        }
    }
}

// ---- per-row: combine 64 tile-maxes -> nn idx -> exact fp32 distance -> -log ----
__global__ __launch_bounds__(256) void nn_reg_kernel(
    const float* __restrict__ q, const unsigned long long* __restrict__ part,
    float* __restrict__ reg_partial)
{
    __shared__ float red[4];
    const int t = threadIdx.x, l = t & 63, w = t >> 6;
    const int row = blockIdx.x * 4 + w;
    unsigned long long p = part[(size_t)l * NPTS + (unsigned)row];
#pragma unroll
    for (int mask = 1; mask < 64; mask <<= 1) {
        const unsigned long long o = __shfl_xor(p, mask);
        if (o > p) p = o;
    }
    const int col = (int)(~(unsigned)(p & 0xFFFFFFFFull));
    const float4* q4 = reinterpret_cast<const float4*>(q);
    const float4 a = q4[row * 64 + l];
    const float4 b = q4[col * 64 + l];
    const float dx = a.x - b.x + 1e-6f;
    const float dy = a.y - b.y + 1e-6f;
    const float dz = a.z - b.z + 1e-6f;
    const float dw = a.w - b.w + 1e-6f;
    float s = dx * dx + dy * dy + dz * dz + dw * dw;
#pragma unroll
    for (int mask = 32; mask; mask >>= 1) s += __shfl_xor(s, mask);
    if (l == 0) red[w] = -0.5f * logf(s);   // -log(sqrt(s))
    __syncthreads();
    if (t == 0) reg_partial[blockIdx.x] = red[0] + red[1] + red[2] + red[3];
}

// ---- final double-precision reduction of partials ---------------------------
__global__ __launch_bounds__(256) void finalize_kernel(
    const float* __restrict__ lp, const float* __restrict__ rp, float* __restrict__ out)
{
    const int t = threadIdx.x, l = t & 63, w = t >> 6;
    double s1 = 0.0, s2 = 0.0;
    for (int i = t; i < 4096; i += 256) s1 += (double)lp[i];
    for (int i = t; i < 2048; i += 256) s2 += (double)rp[i];
#pragma unroll
    for (int mask = 32; mask; mask >>= 1) {
        s1 += __shfl_xor(s1, mask);
        s2 += __shfl_xor(s2, mask);
    }
    __shared__ double r1[4], r2[4];
    if (l == 0) { r1[w] = s1; r2[w] = s2; }
    __syncthreads();
    if (t == 0) {
        out[0] = (float)((r1[0] + r1[1] + r1[2] + r1[3]) / (double)NPTS);
        out[1] = (float)((r2[0] + r2[1] + r2[2] + r2[3]) / (double)NPTS);
    }
}

extern "C" void kernel_launch(void* const* d_in, const int* in_sizes, int n_in,
                              void* d_out, int out_size, void* d_ws, size_t ws_size,
                              hipStream_t stream)
{
    const float* q = (const float*)d_in[0];
    const float* k = (const float*)d_in[1];
    char* ws = (char*)d_ws;
    unsigned short* qbf = (unsigned short*)ws;                          // 4 MB
    unsigned short* kbf = (unsigned short*)(ws + (4u << 20));           // 4 MB
    unsigned long long* part = (unsigned long long*)(ws + (8u << 20));  // [64][8192] u64 = 4 MB
    float* lp = (float*)(ws + (12u << 20));                             // 4096 floats
    float* rp = (float*)(ws + (12u << 20) + (16u << 10));               // 2048 floats
    float* out = (float*)d_out;

    convert_kernel<<<4096, 256, 0, stream>>>(q, k, qbf, kbf);
    sim_kernel<0><<<4096, 256, 0, stream>>>(qbf, kbf, lp, nullptr);     // loss over q.k^T
    sim_kernel<1><<<4096, 256, 0, stream>>>(qbf, qbf, nullptr, part);   // argmax over q.q^T
    nn_reg_kernel<<<2048, 256, 0, stream>>>(q, part, rp);
    finalize_kernel<<<1, 256, 0, stream>>>(lp, rp, out);
}